// Round 7
// baseline (281.320 us; speedup 1.0000x reference)
//
#include <hip/hip_runtime.h>

// Problem constants
#define Bsz 8
#define Tsz 1024
#define Esz 1024
#define Hsz 16
#define DHsz 64
#define NQKV 3072

typedef _Float16 f16x8 __attribute__((ext_vector_type(8)));
typedef _Float16 f16x4 __attribute__((ext_vector_type(4)));
typedef float f32x4 __attribute__((ext_vector_type(4)));
typedef unsigned short u16x8 __attribute__((ext_vector_type(8)));

__device__ __forceinline__ unsigned short f2h(float f) {
    union { _Float16 h; unsigned short u; } cv;
    cv.h = (_Float16)f;
    return cv.u;
}

// v_cvt_pkrtz_f16_f32: pack two f32 -> two f16 (RTZ). Builtin returns __fp16 vector.
__device__ __forceinline__ unsigned int pkh2(float a, float b) {
    typedef __fp16 h16x2 __attribute__((ext_vector_type(2)));
    union { h16x2 v; unsigned int u; } cv;
    cv.v = __builtin_amdgcn_cvt_pkrtz(a, b);
    return cv.u;
}

// async global->LDS DMA, 16B per lane. LDS dest is wave-uniform base + lane*16.
__device__ __forceinline__ void async16(const void* g, void* l) {
    __builtin_amdgcn_global_load_lds(
        (const __attribute__((address_space(1))) void*)g,
        (__attribute__((address_space(3))) void*)l, 16, 0, 0);
}

#define MFMA(a, b, c)   __builtin_amdgcn_mfma_f32_16x16x32_f16((a), (b), (c), 0, 0, 0)
#define MFMA16(a, b, c) __builtin_amdgcn_mfma_f32_16x16x16f16((a), (b), (c), 0, 0, 0)

// ---------------- fused prep kernel ----------------
// blocks [0,8192): cast x f32->f16; [8192,8960): pack Wq/Wk/Wv; [8960,9984): cast Wp.
__global__ __launch_bounds__(256) void prep_kernel(
    const float* __restrict__ x, const float* __restrict__ Wq,
    const float* __restrict__ Wk, const float* __restrict__ Wv,
    const float* __restrict__ Wp,
    unsigned short* __restrict__ xb, unsigned short* __restrict__ Bt,
    unsigned short* __restrict__ wpb)
{
    __shared__ unsigned int tile[64 * 33];
    const int bid = blockIdx.x;
    const int tid = threadIdx.x;

    if (bid < 8192) {
        int i = (bid * 256 + tid) * 4;
        float4 v = *(const float4*)(x + i);
        ushort4 o;
        o.x = f2h(v.x); o.y = f2h(v.y); o.z = f2h(v.z); o.w = f2h(v.w);
        *(ushort4*)(xb + i) = o;
        return;
    }
    if (bid >= 8960) {
        int i = ((bid - 8960) * 256 + tid) * 4;
        float4 v = *(const float4*)(Wp + i);
        ushort4 o;
        o.x = f2h(v.x); o.y = f2h(v.y); o.z = f2h(v.z); o.w = f2h(v.w);
        *(ushort4*)(wpb + i) = o;
        return;
    }
    // pack Wqkv: blk = which(3) x h(16) x etile(16)
    const int blk = bid - 8192;
    const int et = blk & 15, h = (blk >> 4) & 15, which = blk >> 8;
    const float* W = (which == 0) ? Wq : ((which == 1) ? Wk : Wv);
    const float* src = W + ((size_t)h * Esz + et * 64) * DHsz;
#pragma unroll
    for (int it = 0; it < 4; ++it) {
        int task = tid + it * 256;
        int er = task >> 4, ds = task & 15;
        float4 v = *(const float4*)(src + (size_t)er * DHsz + ds * 4);
        tile[er * 33 + ds * 2]     = (unsigned int)f2h(v.x) | ((unsigned int)f2h(v.y) << 16);
        tile[er * 33 + ds * 2 + 1] = (unsigned int)f2h(v.z) | ((unsigned int)f2h(v.w) << 16);
    }
    __syncthreads();
    unsigned short* dst = Bt + ((size_t)(which * 1024 + h * 64)) * Esz + et * 64;
#pragma unroll
    for (int it = 0; it < 2; ++it) {
        int task = tid + it * 256;
        int d = task & 63, es = task >> 6;
        int du = d >> 1, hi = d & 1;
        u16x8 v;
#pragma unroll
        for (int j = 0; j < 8; ++j) {
            unsigned int w = tile[(es * 8 + j) * 33 + du];
            v[j] = (unsigned short)(hi ? (w >> 16) : (w & 0xffffu));
        }
        *(u16x8*)(dst + (size_t)d * Esz + es * 8) = v;
    }
}

// Transpose V columns of qkv [8192, NQKV] -> vT [BH, DH, T], 64x64 tiles via LDS.
// (fallback path only — used when ws_size is too small for a separate vtb region)
__global__ __launch_bounds__(256) void vtrans_kernel(const unsigned short* __restrict__ QKV,
                                                     unsigned short* __restrict__ VT) {
    __shared__ unsigned int tile[64 * 33];
    const int bh = blockIdx.x, tc = blockIdx.y;
    const int b = bh >> 4, h = bh & 15;
    const int tid = threadIdx.x;
    const unsigned short* src = QKV + ((size_t)(b * Tsz) + tc * 64) * NQKV + 2048 + h * 64;
#pragma unroll
    for (int it = 0; it < 2; ++it) {
        int task = tid + it * 256;
        int row = task >> 3, seg = task & 7;
        u16x8 v = *(const u16x8*)(src + (size_t)row * NQKV + seg * 8);
#pragma unroll
        for (int jj = 0; jj < 4; ++jj)
            tile[row * 33 + seg * 4 + jj] =
                (unsigned int)v[2 * jj] | ((unsigned int)v[2 * jj + 1] << 16);
    }
    __syncthreads();
    unsigned short* dst = VT + (size_t)bh * DHsz * Tsz + tc * 64;
#pragma unroll
    for (int it = 0; it < 2; ++it) {
        int task = tid + it * 256;
        int d = task & 63, tseg = task >> 6;
        int du = d >> 1, hi = d & 1;
        u16x8 v;
#pragma unroll
        for (int j = 0; j < 8; ++j) {
            unsigned int w = tile[(tseg * 8 + j) * 33 + du];
            v[j] = (unsigned short)(hi ? (w >> 16) : (w & 0xffffu));
        }
        *(u16x8*)(dst + (size_t)d * Tsz + tseg * 8) = v;
    }
}

// ---------------- GEMM: C[M,N] = A[M,K] * Bt[N,K]^T  (both f16 row-major) ----------------
// Double-buffered LDS staging (raw s_barrier + manual vmcnt(4)), XOR-swizzled segs.
// Swizzle key = (row>>1)&3: conflict-free ds_read_b128 (verified round 4: 6.5M -> 196K).
// MODE 0: LDS = 32768 B exactly (K-loop dbuf) -> 5 blocks/CU (was 34816 B -> 4/CU).
//         Epilogue runs as TWO 64-row passes through a 64x136 u16 tile (8704 shorts,
//         overlays the dbuf), each pass emitting C stores and (if vtg) the fused V^T.
//         __launch_bounds__(256,5): 1536-block grid goes 1.5 -> 1.2 batches.
// MODE 1: unchanged verified path (34816 B, 4/CU; 512 blocks fully resident anyway).
template <int MODE>
__global__ __launch_bounds__(256, (MODE == 0) ? 5 : 4) void gemm_bt(
    const unsigned short* __restrict__ A,
    const unsigned short* __restrict__ Bt,
    int K, int N,
    unsigned short* __restrict__ c16,
    float* __restrict__ outp, const float* __restrict__ bias,
    unsigned short* __restrict__ vtg)
{
    __shared__ unsigned short smem[(MODE == 0) ? 16384 : 17408];
#define SAb(bf) (smem + (bf) * 4096)
#define SBb(bf) (smem + 8192 + (bf) * 4096)
    const int tid = threadIdx.x;
    const int wid = tid >> 6, lane = tid & 63;
    const int quad = lane >> 4, l16 = lane & 15;
    const int col0 = blockIdx.x * 128;
    const int row0 = blockIdx.y * 128;
    const int wm = (wid >> 1) * 64, wn = (wid & 1) * 64;

    const f32x4 zero4 = {0.f, 0.f, 0.f, 0.f};
    f32x4 acc[4][4];
#pragma unroll
    for (int i = 0; i < 4; ++i)
#pragma unroll
        for (int j = 0; j < 4; ++j) acc[i][j] = zero4;

    const unsigned short* gA = A + (size_t)row0 * K;
    const unsigned short* gB = Bt + (size_t)col0 * K;
    const int c0 = wid * 2;              // this wave's 2 chunks (of 8) per tile
    const int srw = lane >> 2;           // row within 16-row chunk
    const int slog = (lane & 3) ^ ((srw >> 1) & 3);  // XOR-swizzled seg (key=row bits 1-2)
    const int xs = (l16 >> 1) & 3;       // read-side swizzle key (row bits 1-2)

    const int KSTEPS = K >> 5;
    // prologue: stage tile 0 into buf 0
#pragma unroll
    for (int cc = 0; cc < 2; ++cc) {
        int c = c0 + cc;
        async16(gA + (size_t)(c * 16 + srw) * K + slog * 8, (void*)(SAb(0) + c * 512 + lane * 8));
        async16(gB + (size_t)(c * 16 + srw) * K + slog * 8, (void*)(SBb(0) + c * 512 + lane * 8));
    }

#pragma unroll 2
    for (int ks = 0; ks < KSTEPS; ++ks) {
        const int cur = ks & 1;
        __builtin_amdgcn_s_barrier();    // B1: prev-iter readers of buf[cur^1] done
        if (ks + 1 < KSTEPS) {
            const int kn = (ks + 1) * 32;
#pragma unroll
            for (int cc = 0; cc < 2; ++cc) {
                int c = c0 + cc;
                async16(gA + (size_t)(c * 16 + srw) * K + kn + slog * 8,
                        (void*)(SAb(cur ^ 1) + c * 512 + lane * 8));
                async16(gB + (size_t)(c * 16 + srw) * K + kn + slog * 8,
                        (void*)(SBb(cur ^ 1) + c * 512 + lane * 8));
            }
            __asm__ volatile("s_waitcnt vmcnt(4)" ::: "memory");
        } else {
            __asm__ volatile("s_waitcnt vmcnt(0)" ::: "memory");
        }
        __builtin_amdgcn_s_barrier();    // B2: tile ks resident for all waves
        __asm__ volatile("" ::: "memory");

        f16x8 af[4], bfr[4];
#pragma unroll
        for (int i = 0; i < 4; ++i)
            af[i] = *(const f16x8*)(SAb(cur) + (wm + i * 16 + l16) * 32 + ((quad ^ xs) * 8));
#pragma unroll
        for (int j = 0; j < 4; ++j)
            bfr[j] = *(const f16x8*)(SBb(cur) + (wn + j * 16 + l16) * 32 + ((quad ^ xs) * 8));
#pragma unroll
        for (int i = 0; i < 4; ++i)
#pragma unroll
            for (int j = 0; j < 4; ++j)
                acc[i][j] = MFMA(af[i], bfr[j], acc[i][j]);
    }
    __syncthreads();                     // all waves done reading before epilogue overlay

    if (MODE == 0) {
        // two 64-row passes: waves with wm == p*64 deposit their f16 sub-tiles into a
        // 64x136 u16 LDS tile, then ALL threads emit coalesced C stores (+ fused V^T).
        unsigned short* ob = c16 + (size_t)row0 * N + col0;
        const bool dovt = (vtg != nullptr) && (col0 >= 2048);
        const int h0 = (col0 - 2048) >> 6;           // first head in tile (tile = 2 heads)
        const int bq = row0 >> 10;                   // batch
        const int t0 = row0 & 1023;                  // t offset within batch
        unsigned short* vb = dovt ? (vtg + ((size_t)(bq * Hsz + h0) * DHsz) * Tsz) : nullptr;
#pragma unroll
        for (int p = 0; p < 2; ++p) {
            __syncthreads();
            if ((wid >> 1) == p) {
#pragma unroll
                for (int i = 0; i < 4; ++i)
#pragma unroll
                    for (int r = 0; r < 4; ++r) {
                        int rowL = i * 16 + quad * 4 + r;        // 0..63 local
                        unsigned short* tr = smem + rowL * 136 + wn + l16;
#pragma unroll
                        for (int j = 0; j < 4; ++j)
                            tr[j * 16] = f2h(acc[i][j][r]);
                    }
            }
            __syncthreads();
            // C store: 64 rows x 128 cols (16 segs of 8)
#pragma unroll
            for (int it = 0; it < 4; ++it) {
                int task = tid + it * 256;
                int rowL = task >> 4, seg = task & 15;
                u16x8 v = *(const u16x8*)(smem + rowL * 136 + seg * 8);
                *(u16x8*)(ob + (size_t)(p * 64 + rowL) * N + seg * 8) = v;
            }
            // fused V-transpose: rows of this pass are t-values t0+p*64+0..63
            if (dovt) {
#pragma unroll
                for (int it = 0; it < 4; ++it) {
                    int task = tid + it * 256;       // 1024 tasks: 128 cols x 8 t-segs
                    int c = task & 127;              // consecutive lanes -> consecutive c
                    int sg = task >> 7;              // t_local = sg*8 + j
                    u16x8 v;
#pragma unroll
                    for (int j = 0; j < 8; ++j)
                        v[j] = smem[(sg * 8 + j) * 136 + c];
                    *(u16x8*)(vb + (size_t)c * Tsz + t0 + p * 64 + sg * 8) = v;
                }
            }
        }
    } else {
        // two passes of 64 rows through a fp32 LDS tile (stride 136 floats)
        float* ft = (float*)smem;
#pragma unroll
        for (int p = 0; p < 2; ++p) {
            __syncthreads();
            if ((wid >> 1) == p) {
#pragma unroll
                for (int i = 0; i < 4; ++i)
#pragma unroll
                    for (int r = 0; r < 4; ++r) {
                        int rowL = i * 16 + quad * 4 + r;
                        float* tr = ft + rowL * 136 + wn + l16;
#pragma unroll
                        for (int j = 0; j < 4; ++j)
                            tr[j * 16] = acc[i][j][r] + bias[col0 + wn + j * 16 + l16];
                    }
            }
            __syncthreads();
#pragma unroll
            for (int it = 0; it < 8; ++it) {
                int task = tid + it * 256;
                int rowL = task >> 5, cs = task & 31;
                float4 v = *(const float4*)(ft + rowL * 136 + cs * 4);
                *(float4*)(outp + (size_t)(row0 + p * 64 + rowL) * N + col0 + cs * 4) = v;
            }
        }
    }
#undef SAb
#undef SBb
}

// ---------------- flash attention: S^T orientation, register-resident P^T, dbuf DMA ----
// (unchanged — verified passing)
__global__ __launch_bounds__(512, 6) void attn_kernel(
    const unsigned short* __restrict__ QKV,
    const unsigned short* __restrict__ VTg,
    unsigned short* __restrict__ AO)
{
    const int bh = blockIdx.x;
    const int pair = blockIdx.y;
    const int b = bh >> 4, h = bh & 15;
    const int tid = threadIdx.x, wid = tid >> 6, lane = tid & 63;
    const int quad = lane >> 4, l16 = lane & 15;

    __shared__ unsigned short smem[16384];
#define SKb(bf) (smem + (bf) * 4096)
#define SVb(bf) (smem + 8192 + (bf) * 4096)

    const unsigned short* Qb = QKV + (size_t)(b * Tsz) * NQKV + h * 64;
    const unsigned short* Kb = QKV + (size_t)(b * Tsz) * NQKV + 1024 + h * 64;
    const unsigned short* VTb = VTg + (size_t)bh * DHsz * Tsz;

    const int srow = lane >> 3;
    const int sseg = lane & 7;
    const int slog = sseg ^ srow;
    const int r0 = wid * 8;
    const int xk = l16 & 7;

    const float C1 = 0.18033688f;        // 0.125 * log2(e)
    const float C2 = -4.32808512f;       // -3.0 * log2(e)
    const f32x4 zero4 = {0.f, 0.f, 0.f, 0.f};

    for (int half = 0; half < 2; ++half) {
        const int qt = (half == 0) ? (7 - pair) : pair;
        const int q0 = qt * 128;
        const int rowlo = q0 + wid * 16;
        const int qrow = rowlo + l16;
        const int nblk = (q0 >> 6) + 2;

        __syncthreads();
        async16(Kb + (size_t)(r0 + srow) * NQKV + slog * 8, (void*)(SKb(0) + r0 * 64 + lane * 8));
        async16(VTb + (size_t)(r0 + srow) * Tsz + slog * 8, (void*)(SVb(0) + r0 * 64 + lane * 8));

        f16x8 qf[2];
#pragma unroll
        for (int kk = 0; kk < 2; ++kk)
            qf[kk] = *(const f16x8*)(Qb + (size_t)qrow * NQKV + kk * 32 + quad * 8);

        f32x4 o[4];
        float lp = 0.f;
#pragma unroll
        for (int dt = 0; dt < 4; ++dt) o[dt] = zero4;

        for (int blk = 0; blk < nblk; ++blk) {
            const int s0 = blk * 64;
            const int cur = blk & 1;
            __builtin_amdgcn_s_barrier();
            if (blk + 1 < nblk) {
                const int sn = (blk + 1) * 64;
                async16(Kb + (size_t)(sn + r0 + srow) * NQKV + slog * 8,
                        (void*)(SKb(cur ^ 1) + r0 * 64 + lane * 8));
                async16(VTb + (size_t)(r0 + srow) * Tsz + sn + slog * 8,
                        (void*)(SVb(cur ^ 1) + r0 * 64 + lane * 8));
                __asm__ volatile("s_waitcnt vmcnt(2)" ::: "memory");
            } else {
                __asm__ volatile("s_waitcnt vmcnt(0)" ::: "memory");
            }
            __builtin_amdgcn_s_barrier();
            __asm__ volatile("" ::: "memory");

            if (s0 > rowlo + 15) continue;

            f32x4 scT[4];
#pragma unroll
            for (int ct = 0; ct < 4; ++ct) scT[ct] = zero4;
#pragma unroll
            for (int kk = 0; kk < 2; ++kk) {
#pragma unroll
                for (int ct = 0; ct < 4; ++ct) {
                    f16x8 kf = *(const f16x8*)(SKb(cur) + (ct * 16 + l16) * 64 +
                                               (((kk * 4 + quad) ^ xk) * 8));
                    scT[ct] = MFMA(kf, qf[kk], scT[ct]);
                }
            }

            f16x4 pk[4];
            const bool full = (s0 + 63 <= rowlo);
#pragma unroll
            for (int ct = 0; ct < 4; ++ct) {
                int sb = s0 + ct * 16 + quad * 4;
                float p[4];
#pragma unroll
                for (int r = 0; r < 4; ++r) {
                    float v = exp2f(fmaf(scT[ct][r], C1, C2));
                    if (!full) v = (sb + r > qrow) ? 0.f : v;
                    p[r] = v;
                    lp += v;
                }
                union { f16x4 v; unsigned int u[2]; } cv;
                cv.u[0] = pkh2(p[0], p[1]);
                cv.u[1] = pkh2(p[2], p[3]);
                pk[ct] = cv.v;
            }

#pragma unroll
            for (int ct = 0; ct < 4; ++ct) {
                const int sl = 2 * ct + (quad >> 1);
#pragma unroll
                for (int dt = 0; dt < 4; ++dt) {
                    f16x4 vf = *(const f16x4*)(SVb(cur) + (dt * 16 + l16) * 64 +
                                               ((sl ^ xk) * 8) + (quad & 1) * 4);
                    o[dt] = MFMA16(vf, pk[ct], o[dt]);
                }
            }
        }

        float s = lp;
        s += __shfl_xor(s, 16, 64);
        s += __shfl_xor(s, 32, 64);
        float inv = 1.0f / s;

        __syncthreads();
        unsigned short* otr = smem;
        const int orow = wid * 16 + l16;
#pragma unroll
        for (int dt = 0; dt < 4; ++dt) {
            *(unsigned int*)(otr + orow * 72 + dt * 16 + quad * 4) =
                pkh2(o[dt][0] * inv, o[dt][1] * inv);
            *(unsigned int*)(otr + orow * 72 + dt * 16 + quad * 4 + 2) =
                pkh2(o[dt][2] * inv, o[dt][3] * inv);
        }
        __syncthreads();
#pragma unroll
        for (int it = 0; it < 2; ++it) {
            int rr = wid * 16 + it * 8 + srow;
            u16x8 v = *(const u16x8*)(otr + rr * 72 + sseg * 8);
            *(u16x8*)(AO + (size_t)(b * Tsz + q0 + rr) * Esz + h * 64 + sseg * 8) = v;
        }
    }
#undef SKb
#undef SVb
}

// ---------------- launch ----------------

extern "C" void kernel_launch(void* const* d_in, const int* in_sizes, int n_in,
                              void* d_out, int out_size, void* d_ws, size_t ws_size,
                              hipStream_t stream)
{
    const float* x  = (const float*)d_in[0];
    const float* Wq = (const float*)d_in[1];
    const float* Wk = (const float*)d_in[2];
    const float* Wv = (const float*)d_in[3];
    const float* Wp = (const float*)d_in[4];
    const float* bp = (const float*)d_in[5];
    float* out = (float*)d_out;

    char* ws = (char*)d_ws;
    unsigned short* xb   = (unsigned short*)(ws);              // 16 MB  x f16 [8192,1024]
    unsigned short* wqkv = (unsigned short*)(ws + 16777216);   //  6 MB  Bt [3072,1024]
    unsigned short* wpb  = (unsigned short*)(ws + 23068672);   //  2 MB  Wp f16
    unsigned short* qkv  = (unsigned short*)(ws + 25165824);   // 48 MB  [8192,3072] f16
    unsigned short* ao   = (unsigned short*)(ws + 75497472);   // 16 MB  attn out [8192,1024]

    // Fused V-transpose needs a dedicated 16 MB vtb region (xb is still live as gemm1's
    // A operand). Fall back to the separate vtrans kernel if ws is too small.
    const bool fused_vt = (ws_size >= (size_t)92274688 + 16777216);
    unsigned short* vtb = fused_vt ? (unsigned short*)(ws + 92274688)
                                   : xb;   // fallback: reuse xb (dead after gemm1)

    prep_kernel<<<9984, 256, 0, stream>>>(x, Wq, Wk, Wv, Wp, xb, wqkv, wpb);

    gemm_bt<0><<<dim3(24, 64), 256, 0, stream>>>(xb, wqkv, 1024, 3072,
                                                 qkv, nullptr, nullptr,
                                                 fused_vt ? vtb : nullptr);

    if (!fused_vt)
        vtrans_kernel<<<dim3(128, 16), 256, 0, stream>>>(qkv, vtb);

    attn_kernel<<<dim3(128, 4), 512, 0, stream>>>(qkv, vtb, ao);

    gemm_bt<1><<<dim3(8, 64), 256, 0, stream>>>(ao, wpb, 1024, 1024,
                                                nullptr, out, bp, nullptr);
}

// Round 8
// 236.995 us; speedup vs baseline: 1.1870x; 1.1870x over previous
//
#include <hip/hip_runtime.h>

// Problem constants
#define Bsz 8
#define Tsz 1024
#define Esz 1024
#define Hsz 16
#define DHsz 64
#define NQKV 3072

typedef _Float16 f16x8 __attribute__((ext_vector_type(8)));
typedef _Float16 f16x4 __attribute__((ext_vector_type(4)));
typedef float f32x4 __attribute__((ext_vector_type(4)));
typedef unsigned short u16x8 __attribute__((ext_vector_type(8)));

__device__ __forceinline__ unsigned short f2h(float f) {
    union { _Float16 h; unsigned short u; } cv;
    cv.h = (_Float16)f;
    return cv.u;
}

// v_cvt_pkrtz_f16_f32: pack two f32 -> two f16 (RTZ). Builtin returns __fp16 vector.
__device__ __forceinline__ unsigned int pkh2(float a, float b) {
    typedef __fp16 h16x2 __attribute__((ext_vector_type(2)));
    union { h16x2 v; unsigned int u; } cv;
    cv.v = __builtin_amdgcn_cvt_pkrtz(a, b);
    return cv.u;
}

// async global->LDS DMA, 16B per lane. LDS dest is wave-uniform base + lane*16.
__device__ __forceinline__ void async16(const void* g, void* l) {
    __builtin_amdgcn_global_load_lds(
        (const __attribute__((address_space(1))) void*)g,
        (__attribute__((address_space(3))) void*)l, 16, 0, 0);
}

#define MFMA(a, b, c)   __builtin_amdgcn_mfma_f32_16x16x32_f16((a), (b), (c), 0, 0, 0)
#define MFMA16(a, b, c) __builtin_amdgcn_mfma_f32_16x16x16f16((a), (b), (c), 0, 0, 0)

// ---------------- fused prep kernel ----------------
// blocks [0,8192): cast x f32->f16; [8192,8960): pack Wq/Wk/Wv; [8960,9984): cast Wp.
__global__ __launch_bounds__(256) void prep_kernel(
    const float* __restrict__ x, const float* __restrict__ Wq,
    const float* __restrict__ Wk, const float* __restrict__ Wv,
    const float* __restrict__ Wp,
    unsigned short* __restrict__ xb, unsigned short* __restrict__ Bt,
    unsigned short* __restrict__ wpb)
{
    __shared__ unsigned int tile[64 * 33];
    const int bid = blockIdx.x;
    const int tid = threadIdx.x;

    if (bid < 8192) {
        int i = (bid * 256 + tid) * 4;
        float4 v = *(const float4*)(x + i);
        ushort4 o;
        o.x = f2h(v.x); o.y = f2h(v.y); o.z = f2h(v.z); o.w = f2h(v.w);
        *(ushort4*)(xb + i) = o;
        return;
    }
    if (bid >= 8960) {
        int i = ((bid - 8960) * 256 + tid) * 4;
        float4 v = *(const float4*)(Wp + i);
        ushort4 o;
        o.x = f2h(v.x); o.y = f2h(v.y); o.z = f2h(v.z); o.w = f2h(v.w);
        *(ushort4*)(wpb + i) = o;
        return;
    }
    // pack Wqkv: blk = which(3) x h(16) x etile(16)
    const int blk = bid - 8192;
    const int et = blk & 15, h = (blk >> 4) & 15, which = blk >> 8;
    const float* W = (which == 0) ? Wq : ((which == 1) ? Wk : Wv);
    const float* src = W + ((size_t)h * Esz + et * 64) * DHsz;
#pragma unroll
    for (int it = 0; it < 4; ++it) {
        int task = tid + it * 256;
        int er = task >> 4, ds = task & 15;
        float4 v = *(const float4*)(src + (size_t)er * DHsz + ds * 4);
        tile[er * 33 + ds * 2]     = (unsigned int)f2h(v.x) | ((unsigned int)f2h(v.y) << 16);
        tile[er * 33 + ds * 2 + 1] = (unsigned int)f2h(v.z) | ((unsigned int)f2h(v.w) << 16);
    }
    __syncthreads();
    unsigned short* dst = Bt + ((size_t)(which * 1024 + h * 64)) * Esz + et * 64;
#pragma unroll
    for (int it = 0; it < 2; ++it) {
        int task = tid + it * 256;
        int d = task & 63, es = task >> 6;
        int du = d >> 1, hi = d & 1;
        u16x8 v;
#pragma unroll
        for (int j = 0; j < 8; ++j) {
            unsigned int w = tile[(es * 8 + j) * 33 + du];
            v[j] = (unsigned short)(hi ? (w >> 16) : (w & 0xffffu));
        }
        *(u16x8*)(dst + (size_t)d * Esz + es * 8) = v;
    }
}

// Transpose V columns of qkv [8192, NQKV] -> vT [BH, DH, T], 64x64 tiles via LDS.
// (fallback path only — used when ws_size is too small for a separate vtb region)
__global__ __launch_bounds__(256) void vtrans_kernel(const unsigned short* __restrict__ QKV,
                                                     unsigned short* __restrict__ VT) {
    __shared__ unsigned int tile[64 * 33];
    const int bh = blockIdx.x, tc = blockIdx.y;
    const int b = bh >> 4, h = bh & 15;
    const int tid = threadIdx.x;
    const unsigned short* src = QKV + ((size_t)(b * Tsz) + tc * 64) * NQKV + 2048 + h * 64;
#pragma unroll
    for (int it = 0; it < 2; ++it) {
        int task = tid + it * 256;
        int row = task >> 3, seg = task & 7;
        u16x8 v = *(const u16x8*)(src + (size_t)row * NQKV + seg * 8);
#pragma unroll
        for (int jj = 0; jj < 4; ++jj)
            tile[row * 33 + seg * 4 + jj] =
                (unsigned int)v[2 * jj] | ((unsigned int)v[2 * jj + 1] << 16);
    }
    __syncthreads();
    unsigned short* dst = VT + (size_t)bh * DHsz * Tsz + tc * 64;
#pragma unroll
    for (int it = 0; it < 2; ++it) {
        int task = tid + it * 256;
        int d = task & 63, tseg = task >> 6;
        int du = d >> 1, hi = d & 1;
        u16x8 v;
#pragma unroll
        for (int j = 0; j < 8; ++j) {
            unsigned int w = tile[(tseg * 8 + j) * 33 + du];
            v[j] = (unsigned short)(hi ? (w >> 16) : (w & 0xffffu));
        }
        *(u16x8*)(dst + (size_t)d * Tsz + tseg * 8) = v;
    }
}

// ---------------- GEMM: C[M,N] = A[M,K] * Bt[N,K]^T  (both f16 row-major) ----------------
// Round-6 verified configuration (gemm1 75.0 µs, MfmaUtil 28, conflicts 196K).
// Round-7's 32KiB/5-block variant REVERTED: the (256,5) bound clamped VGPR 56->48 and
// serialized the fragment loads (MfmaUtil 17, dur 120µs); occupancy was never LDS-bound.
// Swizzle key = (row>>1)&3: conflict-free ds_read_b128 (verified round 4: 6.5M -> 196K).
// MODE 0: f16 C via LDS-transposed coalesced stores; if vtg != nullptr and col0 >= 2048,
//         ALSO emit V^T directly (fuses vtrans). VT task map: c = task&127 (2 lanes/bank,
//         free), seg = task>>7 (verified round 6: 4.1M -> 196K).
// MODE 1: fp32 out + bias.
template <int MODE>
__global__ __launch_bounds__(256, 4) void gemm_bt(
    const unsigned short* __restrict__ A,
    const unsigned short* __restrict__ Bt,
    int K, int N,
    unsigned short* __restrict__ c16,
    float* __restrict__ outp, const float* __restrict__ bias,
    unsigned short* __restrict__ vtg)
{
    // 34816 B: dbuf K-loop uses [0,32768); epilogues overlay the whole buffer.
    __shared__ unsigned short smem[17408];
#define SAb(bf) (smem + (bf) * 4096)
#define SBb(bf) (smem + 8192 + (bf) * 4096)
    const int tid = threadIdx.x;
    const int wid = tid >> 6, lane = tid & 63;
    const int quad = lane >> 4, l16 = lane & 15;
    const int col0 = blockIdx.x * 128;
    const int row0 = blockIdx.y * 128;
    const int wm = (wid >> 1) * 64, wn = (wid & 1) * 64;

    const f32x4 zero4 = {0.f, 0.f, 0.f, 0.f};
    f32x4 acc[4][4];
#pragma unroll
    for (int i = 0; i < 4; ++i)
#pragma unroll
        for (int j = 0; j < 4; ++j) acc[i][j] = zero4;

    const unsigned short* gA = A + (size_t)row0 * K;
    const unsigned short* gB = Bt + (size_t)col0 * K;
    const int c0 = wid * 2;              // this wave's 2 chunks (of 8) per tile
    const int srw = lane >> 2;           // row within 16-row chunk
    const int slog = (lane & 3) ^ ((srw >> 1) & 3);  // XOR-swizzled seg (key=row bits 1-2)
    const int xs = (l16 >> 1) & 3;       // read-side swizzle key (row bits 1-2)

    const int KSTEPS = K >> 5;
    // prologue: stage tile 0 into buf 0
#pragma unroll
    for (int cc = 0; cc < 2; ++cc) {
        int c = c0 + cc;
        async16(gA + (size_t)(c * 16 + srw) * K + slog * 8, (void*)(SAb(0) + c * 512 + lane * 8));
        async16(gB + (size_t)(c * 16 + srw) * K + slog * 8, (void*)(SBb(0) + c * 512 + lane * 8));
    }

#pragma unroll 2
    for (int ks = 0; ks < KSTEPS; ++ks) {
        const int cur = ks & 1;
        __builtin_amdgcn_s_barrier();    // B1: prev-iter readers of buf[cur^1] done
        if (ks + 1 < KSTEPS) {
            const int kn = (ks + 1) * 32;
#pragma unroll
            for (int cc = 0; cc < 2; ++cc) {
                int c = c0 + cc;
                async16(gA + (size_t)(c * 16 + srw) * K + kn + slog * 8,
                        (void*)(SAb(cur ^ 1) + c * 512 + lane * 8));
                async16(gB + (size_t)(c * 16 + srw) * K + kn + slog * 8,
                        (void*)(SBb(cur ^ 1) + c * 512 + lane * 8));
            }
            __asm__ volatile("s_waitcnt vmcnt(4)" ::: "memory");
        } else {
            __asm__ volatile("s_waitcnt vmcnt(0)" ::: "memory");
        }
        __builtin_amdgcn_s_barrier();    // B2: tile ks resident for all waves
        __asm__ volatile("" ::: "memory");

        f16x8 af[4], bfr[4];
#pragma unroll
        for (int i = 0; i < 4; ++i)
            af[i] = *(const f16x8*)(SAb(cur) + (wm + i * 16 + l16) * 32 + ((quad ^ xs) * 8));
#pragma unroll
        for (int j = 0; j < 4; ++j)
            bfr[j] = *(const f16x8*)(SBb(cur) + (wn + j * 16 + l16) * 32 + ((quad ^ xs) * 8));
#pragma unroll
        for (int i = 0; i < 4; ++i)
#pragma unroll
            for (int j = 0; j < 4; ++j)
                acc[i][j] = MFMA(af[i], bfr[j], acc[i][j]);
    }
    __syncthreads();                     // all waves done reading before epilogue overlay

    if (MODE == 0) {
        // C-layout -> f16 LDS tile (stride 136), then coalesced u16x8 stores
#pragma unroll
        for (int i = 0; i < 4; ++i)
#pragma unroll
            for (int r = 0; r < 4; ++r) {
                int rowL = wm + i * 16 + quad * 4 + r;
                unsigned short* tr = smem + rowL * 136 + wn + l16;
#pragma unroll
                for (int j = 0; j < 4; ++j)
                    tr[j * 16] = f2h(acc[i][j][r]);
            }
        __syncthreads();
        unsigned short* ob = c16 + (size_t)row0 * N + col0;
#pragma unroll
        for (int it = 0; it < 8; ++it) {
            int rowG = wid * 32 + it * 4 + quad;
            u16x8 v = *(const u16x8*)(smem + rowG * 136 + l16 * 8);
            *(u16x8*)(ob + (size_t)rowG * N + l16 * 8) = v;
        }
        // fused V-transpose: this tile is V columns -> also write vT [bh][d][t]
        if (vtg != nullptr && col0 >= 2048) {
            const int h0 = (col0 - 2048) >> 6;       // first head in tile (tile = 2 heads)
            const int bq = row0 >> 10;               // batch
            const int t0 = row0 & 1023;              // t offset within batch
            unsigned short* vb = vtg + ((size_t)(bq * Hsz + h0) * DHsz) * Tsz;
#pragma unroll
            for (int it = 0; it < 8; ++it) {
                int task = tid + it * 256;           // 2048 tasks: 128 cols x 16 segs
                int c = task & 127;                  // consecutive lanes -> consecutive c
                int seg = task >> 7;                 // 8 t-values per seg
                u16x8 v;
#pragma unroll
                for (int j = 0; j < 8; ++j)
                    v[j] = smem[(seg * 8 + j) * 136 + c];
                *(u16x8*)(vb + (size_t)c * Tsz + t0 + seg * 8) = v;
            }
        }
    } else {
        // two passes of 64 rows through a fp32 LDS tile (stride 136 floats)
        float* ft = (float*)smem;
#pragma unroll
        for (int p = 0; p < 2; ++p) {
            __syncthreads();
            if ((wid >> 1) == p) {
#pragma unroll
                for (int i = 0; i < 4; ++i)
#pragma unroll
                    for (int r = 0; r < 4; ++r) {
                        int rowL = i * 16 + quad * 4 + r;
                        float* tr = ft + rowL * 136 + wn + l16;
#pragma unroll
                        for (int j = 0; j < 4; ++j)
                            tr[j * 16] = acc[i][j][r] + bias[col0 + wn + j * 16 + l16];
                    }
            }
            __syncthreads();
#pragma unroll
            for (int it = 0; it < 8; ++it) {
                int task = tid + it * 256;
                int rowL = task >> 5, cs = task & 31;
                float4 v = *(const float4*)(ft + rowL * 136 + cs * 4);
                *(float4*)(outp + (size_t)(row0 + p * 64 + rowL) * N + col0 + cs * 4) = v;
            }
        }
    }
#undef SAb
#undef SBb
}

// ---------------- flash attention: S^T orientation, register-resident P^T, dbuf DMA ----
// ONE q-tile per block (was 2 via the half-loop): grid dim3(128,8) = 1024 blocks.
// Rationale (round 7): old 512-block grid capped residency at 2 blocks/CU while
// launch_bounds(512,6)+32KiB LDS allow 3 — occupancy was GRID-limited. 1024 variable-
// length blocks pack 3/CU; and since 128 % 8 == 0, all 8 qt-blocks of one bh land on
// the same XCD -> K/V panels L2-hit across them. Body otherwise identical (verified).
__global__ __launch_bounds__(512, 6) void attn_kernel(
    const unsigned short* __restrict__ QKV,
    const unsigned short* __restrict__ VTg,
    unsigned short* __restrict__ AO)
{
    const int bh = blockIdx.x;
    const int qt = blockIdx.y;
    const int b = bh >> 4, h = bh & 15;
    const int tid = threadIdx.x, wid = tid >> 6, lane = tid & 63;
    const int quad = lane >> 4, l16 = lane & 15;

    __shared__ unsigned short smem[16384];
#define SKb(bf) (smem + (bf) * 4096)
#define SVb(bf) (smem + 8192 + (bf) * 4096)

    const unsigned short* Qb = QKV + (size_t)(b * Tsz) * NQKV + h * 64;
    const unsigned short* Kb = QKV + (size_t)(b * Tsz) * NQKV + 1024 + h * 64;
    const unsigned short* VTb = VTg + (size_t)bh * DHsz * Tsz;

    const int srow = lane >> 3;
    const int sseg = lane & 7;
    const int slog = sseg ^ srow;
    const int r0 = wid * 8;
    const int xk = l16 & 7;

    const float C1 = 0.18033688f;        // 0.125 * log2(e)
    const float C2 = -4.32808512f;       // -3.0 * log2(e)
    const f32x4 zero4 = {0.f, 0.f, 0.f, 0.f};

    const int q0 = qt * 128;
    const int rowlo = q0 + wid * 16;
    const int qrow = rowlo + l16;
    const int nblk = (q0 >> 6) + 2;

    async16(Kb + (size_t)(r0 + srow) * NQKV + slog * 8, (void*)(SKb(0) + r0 * 64 + lane * 8));
    async16(VTb + (size_t)(r0 + srow) * Tsz + slog * 8, (void*)(SVb(0) + r0 * 64 + lane * 8));

    f16x8 qf[2];
#pragma unroll
    for (int kk = 0; kk < 2; ++kk)
        qf[kk] = *(const f16x8*)(Qb + (size_t)qrow * NQKV + kk * 32 + quad * 8);

    f32x4 o[4];
    float lp = 0.f;
#pragma unroll
    for (int dt = 0; dt < 4; ++dt) o[dt] = zero4;

    for (int blk = 0; blk < nblk; ++blk) {
        const int s0 = blk * 64;
        const int cur = blk & 1;
        __builtin_amdgcn_s_barrier();
        if (blk + 1 < nblk) {
            const int sn = (blk + 1) * 64;
            async16(Kb + (size_t)(sn + r0 + srow) * NQKV + slog * 8,
                    (void*)(SKb(cur ^ 1) + r0 * 64 + lane * 8));
            async16(VTb + (size_t)(r0 + srow) * Tsz + sn + slog * 8,
                    (void*)(SVb(cur ^ 1) + r0 * 64 + lane * 8));
            __asm__ volatile("s_waitcnt vmcnt(2)" ::: "memory");
        } else {
            __asm__ volatile("s_waitcnt vmcnt(0)" ::: "memory");
        }
        __builtin_amdgcn_s_barrier();
        __asm__ volatile("" ::: "memory");

        if (s0 > rowlo + 15) continue;

        f32x4 scT[4];
#pragma unroll
        for (int ct = 0; ct < 4; ++ct) scT[ct] = zero4;
#pragma unroll
        for (int kk = 0; kk < 2; ++kk) {
#pragma unroll
            for (int ct = 0; ct < 4; ++ct) {
                f16x8 kf = *(const f16x8*)(SKb(cur) + (ct * 16 + l16) * 64 +
                                           (((kk * 4 + quad) ^ xk) * 8));
                scT[ct] = MFMA(kf, qf[kk], scT[ct]);
            }
        }

        f16x4 pk[4];
        const bool full = (s0 + 63 <= rowlo);
#pragma unroll
        for (int ct = 0; ct < 4; ++ct) {
            int sb = s0 + ct * 16 + quad * 4;
            float p[4];
#pragma unroll
            for (int r = 0; r < 4; ++r) {
                float v = exp2f(fmaf(scT[ct][r], C1, C2));
                if (!full) v = (sb + r > qrow) ? 0.f : v;
                p[r] = v;
                lp += v;
            }
            union { f16x4 v; unsigned int u[2]; } cv;
            cv.u[0] = pkh2(p[0], p[1]);
            cv.u[1] = pkh2(p[2], p[3]);
            pk[ct] = cv.v;
        }

#pragma unroll
        for (int ct = 0; ct < 4; ++ct) {
            const int sl = 2 * ct + (quad >> 1);
#pragma unroll
            for (int dt = 0; dt < 4; ++dt) {
                f16x4 vf = *(const f16x4*)(SVb(cur) + (dt * 16 + l16) * 64 +
                                           ((sl ^ xk) * 8) + (quad & 1) * 4);
                o[dt] = MFMA16(vf, pk[ct], o[dt]);
            }
        }
    }

    float s = lp;
    s += __shfl_xor(s, 16, 64);
    s += __shfl_xor(s, 32, 64);
    float inv = 1.0f / s;

    __syncthreads();
    unsigned short* otr = smem;
    const int orow = wid * 16 + l16;
#pragma unroll
    for (int dt = 0; dt < 4; ++dt) {
        *(unsigned int*)(otr + orow * 72 + dt * 16 + quad * 4) =
            pkh2(o[dt][0] * inv, o[dt][1] * inv);
        *(unsigned int*)(otr + orow * 72 + dt * 16 + quad * 4 + 2) =
            pkh2(o[dt][2] * inv, o[dt][3] * inv);
    }
    __syncthreads();
#pragma unroll
    for (int it = 0; it < 2; ++it) {
        int rr = wid * 16 + it * 8 + srow;
        u16x8 v = *(const u16x8*)(otr + rr * 72 + sseg * 8);
        *(u16x8*)(AO + (size_t)(b * Tsz + q0 + rr) * Esz + h * 64 + sseg * 8) = v;
    }
#undef SKb
#undef SVb
}

// ---------------- launch ----------------

extern "C" void kernel_launch(void* const* d_in, const int* in_sizes, int n_in,
                              void* d_out, int out_size, void* d_ws, size_t ws_size,
                              hipStream_t stream)
{
    const float* x  = (const float*)d_in[0];
    const float* Wq = (const float*)d_in[1];
    const float* Wk = (const float*)d_in[2];
    const float* Wv = (const float*)d_in[3];
    const float* Wp = (const float*)d_in[4];
    const float* bp = (const float*)d_in[5];
    float* out = (float*)d_out;

    char* ws = (char*)d_ws;
    unsigned short* xb   = (unsigned short*)(ws);              // 16 MB  x f16 [8192,1024]
    unsigned short* wqkv = (unsigned short*)(ws + 16777216);   //  6 MB  Bt [3072,1024]
    unsigned short* wpb  = (unsigned short*)(ws + 23068672);   //  2 MB  Wp f16
    unsigned short* qkv  = (unsigned short*)(ws + 25165824);   // 48 MB  [8192,3072] f16
    unsigned short* ao   = (unsigned short*)(ws + 75497472);   // 16 MB  attn out [8192,1024]

    // Fused V-transpose needs a dedicated 16 MB vtb region (xb is still live as gemm1's
    // A operand). Fall back to the separate vtrans kernel if ws is too small.
    const bool fused_vt = (ws_size >= (size_t)92274688 + 16777216);
    unsigned short* vtb = fused_vt ? (unsigned short*)(ws + 92274688)
                                   : xb;   // fallback: reuse xb (dead after gemm1)

    prep_kernel<<<9984, 256, 0, stream>>>(x, Wq, Wk, Wv, Wp, xb, wqkv, wpb);

    gemm_bt<0><<<dim3(24, 64), 256, 0, stream>>>(xb, wqkv, 1024, 3072,
                                                 qkv, nullptr, nullptr,
                                                 fused_vt ? vtb : nullptr);

    if (!fused_vt)
        vtrans_kernel<<<dim3(128, 16), 256, 0, stream>>>(qkv, vtb);

    attn_kernel<<<dim3(128, 8), 512, 0, stream>>>(qkv, vtb, ao);

    gemm_bt<1><<<dim3(8, 64), 256, 0, stream>>>(ao, wpb, 1024, 1024,
                                                nullptr, out, bp, nullptr);
}